// Round 16
// baseline (368.507 us; speedup 1.0000x reference)
//
#include <hip/hip_runtime.h>

#define N_TOKEN 8192
#define N_EMBED 512
#define T_TOKENS 16384
#define KP 1536       // logical packed K = 3 * 512
#define KPM 1024      // memory stride: [hi|lo] 2-segment rows
#define MARGIN 0.45f  // score-gap certainty threshold
#define NBG 16        // nb tiles per top2 block
#define NSLOT 4       // slots per row = 8192 / (128 * NBG)

typedef __bf16 bf16x8 __attribute__((ext_vector_type(8)));
typedef __bf16 bf16x4 __attribute__((ext_vector_type(4)));
typedef float f32x4 __attribute__((ext_vector_type(4)));

// ---------- helpers ----------
__device__ __forceinline__ unsigned int fkey(float f) {
  unsigned int u = __float_as_uint(f);
  return (u & 0x80000000u) ? ~u : (u | 0x80000000u);
}
__device__ __forceinline__ void gl2lds16(const void* gsrc, void* lds) {
  __builtin_amdgcn_global_load_lds(
      (const __attribute__((address_space(1))) unsigned int*)gsrc,
      (__attribute__((address_space(3))) unsigned int*)lds, 16, 0, 0);
}
__device__ __forceinline__ unsigned long long umin64(unsigned long long a,
                                                     unsigned long long b) {
  return a < b ? a : b;
}

// ---------- pack bodies: f32 -> [hi|lo] bf16 ----------
__device__ __forceinline__ void pack_hl_body(const float* __restrict__ src,
                                             __bf16* __restrict__ dstbuf, int gid) {
  int t = gid >> 7, d4 = gid & 127;
  float4 v = reinterpret_cast<const float4*>(src)[gid];
  bf16x4 hi, lo;
  hi[0] = (__bf16)v.x; hi[1] = (__bf16)v.y; hi[2] = (__bf16)v.z; hi[3] = (__bf16)v.w;
  lo[0] = (__bf16)(v.x - (float)hi[0]);
  lo[1] = (__bf16)(v.y - (float)hi[1]);
  lo[2] = (__bf16)(v.z - (float)hi[2]);
  lo[3] = (__bf16)(v.w - (float)hi[3]);
  __bf16* row = dstbuf + (size_t)t * KPM + d4 * 4;
  *(bf16x4*)(row)       = hi;
  *(bf16x4*)(row + 512) = lo;
}

// 2 consecutive float4 per thread (bf16x8 writes)
__device__ __forceinline__ void pack_hl_body2(const float* __restrict__ src,
                                              __bf16* __restrict__ dstbuf, int gid) {
  int f0 = gid * 2;
  int t = f0 >> 7, d4 = f0 & 127;
  float4 v0 = reinterpret_cast<const float4*>(src)[f0];
  float4 v1 = reinterpret_cast<const float4*>(src)[f0 + 1];
  bf16x8 hi, lo;
  hi[0] = (__bf16)v0.x; hi[1] = (__bf16)v0.y; hi[2] = (__bf16)v0.z; hi[3] = (__bf16)v0.w;
  hi[4] = (__bf16)v1.x; hi[5] = (__bf16)v1.y; hi[6] = (__bf16)v1.z; hi[7] = (__bf16)v1.w;
  lo[0] = (__bf16)(v0.x - (float)hi[0]);
  lo[1] = (__bf16)(v0.y - (float)hi[1]);
  lo[2] = (__bf16)(v0.z - (float)hi[2]);
  lo[3] = (__bf16)(v0.w - (float)hi[3]);
  lo[4] = (__bf16)(v1.x - (float)hi[4]);
  lo[5] = (__bf16)(v1.y - (float)hi[5]);
  lo[6] = (__bf16)(v1.z - (float)hi[6]);
  lo[7] = (__bf16)(v1.w - (float)hi[7]);
  __bf16* row = dstbuf + (size_t)t * KPM + d4 * 4;
  *(bf16x8*)(row)       = hi;
  *(bf16x8*)(row + 512) = lo;
}

__device__ __forceinline__ void pack_k_body(const float* __restrict__ kw,
                                            __bf16* __restrict__ kp,
                                            float* __restrict__ h,
                                            int blk, int tid) {
  int row = blk * 4 + (tid >> 6);
  int lane = tid & 63;
  const float4* src = reinterpret_cast<const float4*>(kw + (size_t)row * N_EMBED);
  __bf16* dst = kp + (size_t)row * KPM;
  float s = 0.f;
  #pragma unroll
  for (int c = 0; c < 2; ++c) {
    int f4 = lane + c * 64;
    float4 v = src[f4];
    s += v.x*v.x + v.y*v.y + v.z*v.z + v.w*v.w;
    bf16x4 hi, lo;
    hi[0] = (__bf16)v.x; hi[1] = (__bf16)v.y; hi[2] = (__bf16)v.z; hi[3] = (__bf16)v.w;
    lo[0] = (__bf16)(v.x - (float)hi[0]);
    lo[1] = (__bf16)(v.y - (float)hi[1]);
    lo[2] = (__bf16)(v.z - (float)hi[2]);
    lo[3] = (__bf16)(v.w - (float)hi[3]);
    *(bf16x4*)(dst + f4 * 4)       = hi;
    *(bf16x4*)(dst + 512 + f4 * 4) = lo;
  }
  #pragma unroll
  for (int off = 32; off; off >>= 1) s += __shfl_down(s, off);
  if (lane == 0) h[row] = 0.5f * s;
}

// ---------- fused prep: pack_x(2x) | pack_k+norm | sum(ema_n)+init ----------
__global__ void k_pack_all(const float* __restrict__ x, const float* __restrict__ kw,
                           const float* __restrict__ ema_n,
                           __bf16* __restrict__ xp, __bf16* __restrict__ kp,
                           float* __restrict__ h, float* __restrict__ nsum,
                           unsigned int* __restrict__ ucount, int* __restrict__ counts) {
  int b = blockIdx.x;
  if (b < 4096) {
    pack_hl_body2(x, xp, b * 256 + threadIdx.x);
  } else if (b < 6144) {
    pack_k_body(kw, kp, h, b - 4096, threadIdx.x);
  } else if (b == 6144) {
    __shared__ float sm[256];
    float s = 0.f;
    for (int i = threadIdx.x; i < N_TOKEN; i += 256) s += ema_n[i];
    sm[threadIdx.x] = s;
    __syncthreads();
    for (int off = 128; off; off >>= 1) {
      if (threadIdx.x < off) sm[threadIdx.x] += sm[threadIdx.x + off];
      __syncthreads();
    }
    if (threadIdx.x == 0) { *nsum = sm[0]; *ucount = 0u; }
  } else {
    for (int i = threadIdx.x; i < N_TOKEN; i += 256) counts[i] = 0;
  }
}

// ---------- standalone packs (fallback paths) ----------
__global__ void k_pack_x(const float* __restrict__ x, __bf16* __restrict__ xp) {
  pack_hl_body(x, xp, blockIdx.x * blockDim.x + threadIdx.x);
}
__global__ void k_pack_k_norm(const float* __restrict__ kw, __bf16* __restrict__ kp,
                              float* __restrict__ h) {
  pack_k_body(kw, kp, h, blockIdx.x, threadIdx.x);
}

// ---------- norms only (deep fallback) ----------
__global__ void k_hnorm(const float* __restrict__ key_w, float* __restrict__ h) {
  int code = blockIdx.x * 4 + (threadIdx.x >> 6);
  int lane = threadIdx.x & 63;
  const float4* row = reinterpret_cast<const float4*>(key_w + (size_t)code * N_EMBED);
  float s = 0.f;
  float4 v0 = row[lane];
  float4 v1 = row[lane + 64];
  s += v0.x*v0.x + v0.y*v0.y + v0.z*v0.z + v0.w*v0.w;
  s += v1.x*v1.x + v1.y*v1.y + v1.z*v1.z + v1.w*v1.w;
  #pragma unroll
  for (int off = 32; off; off >>= 1) s += __shfl_down(s, off);
  if (lane == 0) h[code] = 0.5f * s;
}

#define BMr 128
#define BNr 128
#define BKe 64   // refine K-step (128 B rows)

// ---------- PASS 1: K=512 hi*hi GEMM; BK=128; 16 nb tiles/block; grid 512 ----
// One co-resident block-wave (2 blocks/CU x 256 CU). XCD A-band locality.
__global__ __launch_bounds__(256, 2) void k_mfma_top2(
    const __bf16* __restrict__ xp, const __bf16* __restrict__ kp,
    const float* __restrict__ h, float4* __restrict__ slots) {
  __shared__ __bf16 AS[128 * 128];  // 32 KB, 256 B rows
  __shared__ __bf16 BS[128 * 128];  // 32 KB

  const int b = blockIdx.x;
  const int xcd = b & 7, chunk = b >> 3;        // 512 blocks: chunk 0..63
  const int mb = xcd * 16 + (chunk & 15);
  const int nbg = chunk >> 4;                   // 0..3
  const int m0 = mb * BMr;
  const int tid = threadIdx.x;
  const int lane = tid & 63;
  const int wid = tid >> 6;
  const int wm = wid * 32;           // 4 waves x 32 rows
  const int soff = tid * 16;
  const int rgrp = lane >> 4;
  const int cidx = lane & 15;

  float rs1[8], rs2[8];
  int rc1[8];
  #pragma unroll
  for (int u = 0; u < 8; ++u) { rs1[u] = 3.4e38f; rs2[u] = 3.4e38f; rc1[u] = 0; }

  for (int q = 0; q < NBG; ++q) {
    const int n0 = (nbg * NBG + q) * BNr;
    f32x4 acc[2][8] = {};

    for (int ks = 0; ks < 512; ks += 128) {   // hi columns, 256 B rows
      __syncthreads();
      #pragma unroll
      for (int i = 0; i < 8; ++i) {
        int off = i * 4096 + soff;
        int row = off >> 8;
        int inner = (off & 255) ^ ((row & 7) << 4);
        gl2lds16(xp + (size_t)(m0 + row) * KPM + ks + (inner >> 1), (char*)AS + off);
        gl2lds16(kp + (size_t)(n0 + row) * KPM + ks + (inner >> 1), (char*)BS + off);
      }
      asm volatile("s_waitcnt vmcnt(0)" ::: "memory");
      __syncthreads();

      #pragma unroll
      for (int kk = 0; kk < 4; ++kk) {
        const int cbyte = kk * 64 + (lane >> 4) * 16;
        bf16x8 af[2], bb[8];
        #pragma unroll
        for (int i = 0; i < 2; ++i) {
          int arow = wm + i * 16 + (lane & 15);
          af[i] = *(const bf16x8*)((const char*)AS + arow * 256 + (cbyte ^ ((arow & 7) << 4)));
        }
        #pragma unroll
        for (int j = 0; j < 8; ++j) {
          int brow = j * 16 + (lane & 15);
          bb[j] = *(const bf16x8*)((const char*)BS + brow * 256 + (cbyte ^ ((brow & 7) << 4)));
        }
        #pragma unroll
        for (int i = 0; i < 2; ++i)
          #pragma unroll
          for (int j = 0; j < 8; ++j)
            acc[i][j] = __builtin_amdgcn_mfma_f32_16x16x32_bf16(af[i], bb[j], acc[i][j], 0, 0, 0);
      }
    }

    // insert this tile's 8 scores per output row into running top-2
    #pragma unroll
    for (int i = 0; i < 2; ++i) {
      #pragma unroll
      for (int r = 0; r < 4; ++r) {
        const int u = i * 4 + r;
        float s1 = rs1[u], s2 = rs2[u];
        int c1 = rc1[u];
        #pragma unroll
        for (int j = 0; j < 8; ++j) {
          int kk = n0 + j * 16 + cidx;
          float sc = h[kk] - acc[i][j][r];
          if (sc < s1) { s2 = s1; s1 = sc; c1 = kk; }
          else s2 = fminf(s2, sc);
        }
        rs1[u] = s1; rs2[u] = s2; rc1[u] = c1;
      }
    }
  }

  // one butterfly per output row; slot per (row, nbg)
  #pragma unroll
  for (int u = 0; u < 8; ++u) {
    float s1 = rs1[u], s2 = rs2[u];
    int c1 = rc1[u];
    #pragma unroll
    for (int msk = 1; msk < 16; msk <<= 1) {
      float o1 = __shfl_xor(s1, msk);
      float o2 = __shfl_xor(s2, msk);
      int   oc = __shfl_xor(c1, msk);
      float ns2 = fminf(fminf(s2, o2), fmaxf(s1, o1));
      bool take = o1 < s1;
      s1 = take ? o1 : s1;
      c1 = take ? oc : c1;
      s2 = ns2;
    }
    if (cidx == 0) {
      int row = m0 + wm + (u >> 2) * 16 + rgrp * 4 + (u & 3);
      float4 p;
      p.x = s1; p.y = s2; p.z = __int_as_float(c1); p.w = 0.f;
      slots[(size_t)row * NSLOT + nbg] = p;
    }
  }
}

// ---------- reduce: global top-2 (4 slots) -> certain idx (+count) or list ---
__global__ void k_top2_reduce(const float4* __restrict__ slots,
                              int* __restrict__ idx, unsigned int* __restrict__ tlist,
                              unsigned int* __restrict__ ucount,
                              int* __restrict__ counts,
                              unsigned long long* __restrict__ rbest) {
  int tid = threadIdx.x;
  int lane = tid & 63, wid = tid >> 6;
  int row = blockIdx.x * 64 + wid * 16 + (lane >> 2);
  int slot = lane & 3;
  float4 a = slots[(size_t)row * NSLOT + slot];
  float s1 = a.x, s2 = a.y;
  int c1 = __float_as_int(a.z);
  #pragma unroll
  for (int msk = 1; msk < 4; msk <<= 1) {
    float o1 = __shfl_xor(s1, msk);
    float o2 = __shfl_xor(s2, msk);
    int   oc = __shfl_xor(c1, msk);
    float ns2 = fminf(fminf(s2, o2), fmaxf(s1, o1));
    bool take = o1 < s1;
    s1 = take ? o1 : s1;
    c1 = take ? oc : c1;
    s2 = ns2;
  }
  if (slot == 0) {
    if (s2 - s1 >= MARGIN) {
      idx[row] = c1;
      atomicAdd(&counts[c1], 1);
    } else {
      unsigned int p = atomicAdd(ucount, 1u);
      tlist[p] = (unsigned int)row;
      rbest[p] = ~0ull;   // init for refine's atomicMin
    }
  }
}

// ---------- REFINE: 3-term K=1536 GEMM over uncertain tokens (mb-stride) ----
__global__ __launch_bounds__(256) void k_mfma_refine(
    const __bf16* __restrict__ xp, const __bf16* __restrict__ kp,
    const float* __restrict__ h, const unsigned int* __restrict__ tlist,
    const unsigned int* __restrict__ ucount, unsigned long long* __restrict__ rbest) {
  const unsigned int uc = *ucount;
  const int nb = blockIdx.x;
  const int n0 = nb * BNr;
  const int tid = threadIdx.x;
  const int lane = tid & 63;
  const int wid = tid >> 6;
  const int wm = (wid >> 1) * 64, wn = (wid & 1) * 64;
  const int r0 = tid >> 3;  // 0..31
  const int soff = tid * 16;
  const int innerC = (soff & 127) ^ ((r0 & 7) << 4);
  const int rgrp = lane >> 4;
  const int cidx = lane & 15;

  __shared__ __bf16 AS[BMr * BKe];
  __shared__ __bf16 BS[BNr * BKe];

  for (int mb = blockIdx.y; mb * BMr < (int)uc; mb += 16) {
    const int m0 = mb * BMr;
    size_t abase[4];
    #pragma unroll
    for (int i = 0; i < 4; ++i) {
      int p = m0 + r0 + 32 * i;
      int pc = p < (int)uc ? p : (int)uc - 1;
      abase[i] = (size_t)tlist[pc] * KPM;
    }

    f32x4 acc[4][4] = {};
    for (int ks = 0; ks < KP; ks += BKe) {
      const int ksA = ks < 512 ? ks : ks - 512;     // [hi|hi|lo]
      const int ksB = ks < 1024 ? ks : ks - 1024;   // [hi|lo|hi]
      __syncthreads();
      #pragma unroll
      for (int i = 0; i < 4; ++i) {
        int off = i * 4096 + soff;
        int brow = (off >> 7);
        gl2lds16(xp + abase[i] + ksA + (innerC >> 1), (char*)AS + off);
        int binner = (off & 127) ^ ((brow & 7) << 4);
        gl2lds16(kp + (size_t)(n0 + brow) * KPM + ksB + (binner >> 1), (char*)BS + off);
      }
      asm volatile("s_waitcnt vmcnt(0)" ::: "memory");
      __syncthreads();

      #pragma unroll
      for (int kk = 0; kk < 2; ++kk) {
        const int cbyte = kk * 64 + (lane >> 4) * 16;
        bf16x8 af[4], bb[4];
        #pragma unroll
        for (int i = 0; i < 4; ++i) {
          int arow = wm + i * 16 + (lane & 15);
          af[i] = *(const bf16x8*)((const char*)AS + arow * 128 + (cbyte ^ ((arow & 7) << 4)));
          int brow = wn + i * 16 + (lane & 15);
          bb[i] = *(const bf16x8*)((const char*)BS + brow * 128 + (cbyte ^ ((brow & 7) << 4)));
        }
        #pragma unroll
        for (int i = 0; i < 4; ++i)
          #pragma unroll
          for (int j = 0; j < 4; ++j)
            acc[i][j] = __builtin_amdgcn_mfma_f32_16x16x32_bf16(af[i], bb[j], acc[i][j], 0, 0, 0);
      }
    }

    #pragma unroll
    for (int i = 0; i < 4; ++i) {
      #pragma unroll
      for (int r = 0; r < 4; ++r) {
        unsigned long long m = ~0ull;
        #pragma unroll
        for (int j = 0; j < 4; ++j) {
          int kk = n0 + wn + j * 16 + cidx;
          float score = h[kk] - acc[i][j][r];
          unsigned long long cand =
              ((unsigned long long)fkey(score) << 32) | (unsigned int)kk;
          m = umin64(m, cand);
        }
        #pragma unroll
        for (int msk = 1; msk < 16; msk <<= 1) m = umin64(m, __shfl_xor(m, msk));
        if (cidx == 0) {
          int p = m0 + wm + i * 16 + rgrp * 4 + r;
          if ((unsigned int)p < uc) atomicMin(&rbest[p], m);
        }
      }
    }
    __syncthreads();  // LDS safe before next mb iteration's stores
  }
}

// ---------- finalize: uncertain rows get refined index (+count) ----------
__global__ void k_finalize(const unsigned long long* __restrict__ rbest,
                           const unsigned int* __restrict__ tlist,
                           const unsigned int* __restrict__ ucount,
                           int* __restrict__ idx, int* __restrict__ counts) {
  unsigned int p = blockIdx.x * 256 + threadIdx.x;
  if (p < *ucount) {
    int k = (int)(unsigned int)(rbest[p] & 0xffffffffull);
    idx[tlist[p]] = k;
    atomicAdd(&counts[k], 1);
  }
}

// ---------- counting-sort CSR + fused EMA update ----------
__global__ void k_scan(const int* __restrict__ counts, int* __restrict__ offs,
                       int* __restrict__ cursor) {
  __shared__ int sa[256], sb[256];
  int tid = threadIdx.x;
  int base = tid * 32;
  int loc[32]; int s = 0;
  #pragma unroll
  for (int e = 0; e < 32; ++e) { loc[e] = s; s += counts[base + e]; }
  sa[tid] = s;
  __syncthreads();
  int* src = sa; int* dst = sb;
  for (int d = 1; d < 256; d <<= 1) {
    int v = src[tid] + (tid >= d ? src[tid - d] : 0);
    dst[tid] = v;
    __syncthreads();
    int* tmp = src; src = dst; dst = tmp;
  }
  int excl = src[tid] - s;
  #pragma unroll
  for (int e = 0; e < 32; ++e) {
    int o = excl + loc[e];
    offs[base + e] = o;
    cursor[base + e] = o;
  }
}

__global__ void k_place(const int* __restrict__ idx, int* __restrict__ cursor,
                        int* __restrict__ tok) {
  int t = blockIdx.x * 256 + threadIdx.x;
  if (t < T_TOKENS) {
    int p = atomicAdd(&cursor[idx[t]], 1);
    tok[p] = t;
  }
}

// one wave per code: en; ew; kw; and quantized for each token (fused).
__global__ void k_update(const float* __restrict__ x, const float* __restrict__ ema_n,
                         const float* __restrict__ ema_w, const float* __restrict__ value_w,
                         const int* __restrict__ counts,
                         const int* __restrict__ offs, const int* __restrict__ tok,
                         const float* __restrict__ nsum,
                         float* __restrict__ out_en, float* __restrict__ out_ew,
                         float* __restrict__ out_kw, float* __restrict__ out_q) {
  int k = blockIdx.x * 4 + (threadIdx.x >> 6);
  int lane = threadIdx.x & 63;
  int cnt = counts[k];
  int off = offs[k];
  float en = 0.99f * ema_n[k] + 0.005f * (float)cnt;
  if (lane == 0) out_en[k] = en;
  float n = 0.99f * (*nsum) + 81.92f;   // 0.005 * 16384
  float sz = (en + 1e-8f) / (n + 1e-8f * (float)N_TOKEN) * n;

  const float4* er = reinterpret_cast<const float4*>(ema_w + (size_t)k * N_EMBED);
  float4 e0 = er[lane], e1 = er[lane + 64];
  const float4* vr = reinterpret_cast<const float4*>(value_w + (size_t)k * N_EMBED);
  float4 v0 = vr[lane], v1 = vr[lane + 64];
  float4 s0 = {0.f, 0.f, 0.f, 0.f}, s1v = {0.f, 0.f, 0.f, 0.f};
  for (int q = 0; q < cnt; ++q) {
    int t = tok[off + q];
    const float4* xr = reinterpret_cast<const float4*>(x + (size_t)t * N_EMBED);
    float4 a = xr[lane], b = xr[lane + 64];
    s0.x += a.x; s0.y += a.y; s0.z += a.z; s0.w += a.w;
    s1v.x += b.x; s1v.y += b.y; s1v.z += b.z; s1v.w += b.w;
    float4 qa, qb;
    qa.x = a.x + v0.x; qa.y = a.y + v0.y; qa.z = a.z + v0.z; qa.w = a.w + v0.w;
    qb.x = b.x + v1.x; qb.y = b.y + v1.y; qb.z = b.z + v1.z; qb.w = b.w + v1.w;
    float4* oq = reinterpret_cast<float4*>(out_q + (size_t)t * N_EMBED);
    oq[lane] = qa; oq[lane + 64] = qb;
  }
  float4 w0, w1;
  w0.x = 0.99f * e0.x + 0.005f * s0.x;  w0.y = 0.99f * e0.y + 0.005f * s0.y;
  w0.z = 0.99f * e0.z + 0.005f * s0.z;  w0.w = 0.99f * e0.w + 0.005f * s0.w;
  w1.x = 0.99f * e1.x + 0.005f * s1v.x; w1.y = 0.99f * e1.y + 0.005f * s1v.y;
  w1.z = 0.99f * e1.z + 0.005f * s1v.z; w1.w = 0.99f * e1.w + 0.005f * s1v.w;
  float4* ow = reinterpret_cast<float4*>(out_ew + (size_t)k * N_EMBED);
  ow[lane] = w0; ow[lane + 64] = w1;
  float4 q0, q1;
  q0.x = w0.x / sz; q0.y = w0.y / sz; q0.z = w0.z / sz; q0.w = w0.w / sz;
  q1.x = w1.x / sz; q1.y = w1.y / sz; q1.z = w1.z / sz; q1.w = w1.w / sz;
  float4* okw = reinterpret_cast<float4*>(out_kw + (size_t)k * N_EMBED);
  okw[lane] = q0; okw[lane + 64] = q1;
}

// ---------- quantized = x + value_w[idx] (fallback paths only) ----------
__global__ void k_quant(const float* __restrict__ x, const float* __restrict__ value_w,
                        const int* __restrict__ idx, float* __restrict__ q) {
  int gid = blockIdx.x * blockDim.x + threadIdx.x;
  int t = gid >> 7, d4 = gid & 127;
  float4 xv = reinterpret_cast<const float4*>(x)[gid];
  float4 v = reinterpret_cast<const float4*>(value_w + (size_t)idx[t] * N_EMBED)[d4];
  float4 o;
  o.x = xv.x + v.x; o.y = xv.y + v.y; o.z = xv.z + v.z; o.w = xv.w + v.w;
  reinterpret_cast<float4*>(q)[gid] = o;
}

// ---------- single-stage MFMA GEMM + argmin (ws fallback; [hi|lo] remap) -----
__global__ __launch_bounds__(256) void k_mfma_argmin(
    const __bf16* __restrict__ xp, const __bf16* __restrict__ kp,
    const float* __restrict__ h, unsigned long long* __restrict__ best) {
  __shared__ __bf16 AS[BMr * BKe];
  __shared__ __bf16 BS[BNr * BKe];
  const int nb = blockIdx.x, mb = blockIdx.y;
  const int m0 = mb * BMr, n0 = nb * BNr;
  const int tid = threadIdx.x;
  const int lane = tid & 63;
  const int wid = tid >> 6;
  const int wm = (wid >> 1) * 64, wn = (wid & 1) * 64;
  f32x4 acc[4][4] = {};
  const int soff = tid * 16;
  for (int ks = 0; ks < KP; ks += BKe) {
    const int ksA = ks < 512 ? ks : ks - 512;
    const int ksB = ks < 1024 ? ks : ks - 1024;
    __syncthreads();
    #pragma unroll
    for (int i = 0; i < 4; ++i) {
      int off = i * 4096 + soff;
      int row = off >> 7;
      int inner = (off & 127) ^ ((row & 7) << 4);
      gl2lds16(xp + (size_t)(m0 + row) * KPM + ksA + (inner >> 1), (char*)AS + off);
      gl2lds16(kp + (size_t)(n0 + row) * KPM + ksB + (inner >> 1), (char*)BS + off);
    }
    asm volatile("s_waitcnt vmcnt(0)" ::: "memory");
    __syncthreads();
    #pragma unroll
    for (int kk = 0; kk < 2; ++kk) {
      const int cbyte = kk * 64 + (lane >> 4) * 16;
      bf16x8 af[4], bb[4];
      #pragma unroll
      for (int i = 0; i < 4; ++i) {
        int arow = wm + i * 16 + (lane & 15);
        af[i] = *(const bf16x8*)((const char*)AS + arow * 128 + (cbyte ^ ((arow & 7) << 4)));
        int brow = wn + i * 16 + (lane & 15);
        bb[i] = *(const bf16x8*)((const char*)BS + brow * 128 + (cbyte ^ ((brow & 7) << 4)));
      }
      #pragma unroll
      for (int i = 0; i < 4; ++i)
        #pragma unroll
        for (int j = 0; j < 4; ++j)
          acc[i][j] = __builtin_amdgcn_mfma_f32_16x16x32_bf16(af[i], bb[j], acc[i][j], 0, 0, 0);
    }
  }
  const int rgrp = lane >> 4;
  const int cidx = lane & 15;
  #pragma unroll
  for (int i = 0; i < 4; ++i) {
    #pragma unroll
    for (int r = 0; r < 4; ++r) {
      unsigned long long m = ~0ull;
      #pragma unroll
      for (int j = 0; j < 4; ++j) {
        int kk = n0 + wn + j * 16 + cidx;
        float score = h[kk] - acc[i][j][r];
        unsigned long long cand =
            ((unsigned long long)fkey(score) << 32) | (unsigned int)kk;
        m = umin64(m, cand);
      }
      #pragma unroll
      for (int msk = 1; msk < 16; msk <<= 1) m = umin64(m, __shfl_xor(m, msk));
      if (cidx == 0) {
        int row = m0 + wm + i * 16 + rgrp * 4 + r;
        atomicMin(&best[row], m);
      }
    }
  }
}

// ---------- f32 fallback GEMM+argmin ----------
#define BT 128
#define BK 128
#define DC 32
__global__ __launch_bounds__(256, 2) void k_gemm_argmin(
    const float* __restrict__ x, const float* __restrict__ key_w,
    const float* __restrict__ h, unsigned long long* __restrict__ best) {
  __shared__ float4 XS[BT * 8];
  __shared__ float4 KS[BK * 8];
  const int kb = blockIdx.x, tb = blockIdx.y;
  const int t0 = tb * BT, k0 = kb * BK;
  const int tid = threadIdx.x;
  const int tx = tid & 15;
  const int tyg = tid >> 4;
  float acc[8][8];
  #pragma unroll
  for (int i = 0; i < 8; ++i)
    #pragma unroll
    for (int j = 0; j < 8; ++j) acc[i][j] = 0.f;
  for (int dc = 0; dc < N_EMBED; dc += DC) {
    __syncthreads();
    #pragma unroll
    for (int ld = 0; ld < 4; ++ld) {
      int li = ld * 256 + tid;
      int row = li >> 3, c4 = li & 7;
      XS[row * 8 + (c4 ^ (row & 7))] =
          *reinterpret_cast<const float4*>(x + (size_t)(t0 + row) * N_EMBED + dc + c4 * 4);
      KS[row * 8 + (c4 ^ (row & 7))] =
          *reinterpret_cast<const float4*>(key_w + (size_t)(k0 + row) * N_EMBED + dc + c4 * 4);
    }
    __syncthreads();
    #pragma unroll
    for (int d4 = 0; d4 < 8; ++d4) {
      float4 a[8], b[8];
      #pragma unroll
      for (int j = 0; j < 8; ++j) {
        a[j] = XS[(tyg + 16 * j) * 8 + (d4 ^ (tyg & 7))];
        b[j] = KS[(tx  + 16 * j) * 8 + (d4 ^ (tx  & 7))];
      }
      #pragma unroll
      for (int i = 0; i < 8; ++i) {
        float4 av = a[i];
        #pragma unroll
        for (int j = 0; j < 8; ++j) {
          float4 bv = b[j];
          acc[i][j] = fmaf(av.x, bv.x, fmaf(av.y, bv.y,
                      fmaf(av.z, bv.z, fmaf(av.w, bv.w, acc[i][j]))));
        }
      }
    }
  }
  #pragma unroll
  for (int i = 0; i < 8; ++i) {
    unsigned long long m = ~0ull;
    #pragma unroll
    for (int j = 0; j < 8; ++j) {
      int kk = k0 + tx + 16 * j;
      float score = h[kk] - acc[i][j];
      unsigned long long cand =
          ((unsigned long long)fkey(score) << 32) | (unsigned int)kk;
      m = umin64(m, cand);
    }
    #pragma unroll
    for (int mask = 1; mask < 16; mask <<= 1) m = umin64(m, __shfl_xor(m, mask));
    if (tx == 0) atomicMin(&best[t0 + tyg + 16 * i], m);
  }
}

// ---------- legacy aux (fallback paths) ----------
__global__ void k_extract_counts(const unsigned long long* __restrict__ best,
                                 int* __restrict__ idx, float* __restrict__ out_en) {
  int t = blockIdx.x * blockDim.x + threadIdx.x;
  if (t < T_TOKENS) {
    int k = (int)(unsigned int)(best[t] & 0xffffffffull);
    idx[t] = k;
    atomicAdd(&out_en[k], 0.005f);
  }
}
__global__ void k_quant_scatter(const float* __restrict__ x,
                                const float* __restrict__ value_w,
                                const int* __restrict__ idx,
                                float* __restrict__ q, float* __restrict__ out_ew) {
  int gid = blockIdx.x * blockDim.x + threadIdx.x;
  int t = gid >> 7, d4 = gid & 127;
  float4 xv = reinterpret_cast<const float4*>(x)[gid];
  int k = idx[t];
  float4 v = reinterpret_cast<const float4*>(value_w + (size_t)k * N_EMBED)[d4];
  float4 o;
  o.x = xv.x + v.x; o.y = xv.y + v.y; o.z = xv.z + v.z; o.w = xv.w + v.w;
  reinterpret_cast<float4*>(q)[gid] = o;
  const float c = 0.005f;
  float* dst = out_ew + (size_t)k * N_EMBED + d4 * 4;
  atomicAdd(dst + 0, c * xv.x);
  atomicAdd(dst + 1, c * xv.y);
  atomicAdd(dst + 2, c * xv.z);
  atomicAdd(dst + 3, c * xv.w);
}
__global__ void k_scaleN(const float* __restrict__ ema_n, float* __restrict__ out_en) {
  int k = blockIdx.x * blockDim.x + threadIdx.x;
  if (k < N_TOKEN) out_en[k] = 0.99f * ema_n[k];
}
__global__ void k_scaleW(const float* __restrict__ ema_w, float* __restrict__ out_ew) {
  int gid = blockIdx.x * blockDim.x + threadIdx.x;
  float4 v = reinterpret_cast<const float4*>(ema_w)[gid];
  float4 o;
  o.x = 0.99f * v.x; o.y = 0.99f * v.y; o.z = 0.99f * v.z; o.w = 0.99f * v.w;
  reinterpret_cast<float4*>(out_ew)[gid] = o;
}
__global__ void k_sumn(const float* __restrict__ en, float* __restrict__ nsum) {
  __shared__ float sm[256];
  float s = 0.f;
  for (int i = threadIdx.x; i < N_TOKEN; i += 256) s += en[i];
  sm[threadIdx.x] = s;
  __syncthreads();
  for (int off = 128; off; off >>= 1) {
    if (threadIdx.x < off) sm[threadIdx.x] += sm[threadIdx.x + off];
    __syncthreads();
  }
  if (threadIdx.x == 0) *nsum = sm[0];
}
__global__ void k_keyw(const float* __restrict__ out_ew, const float* __restrict__ out_en,
                       const float* __restrict__ nsum, float* __restrict__ out_kw) {
  int gid = blockIdx.x * blockDim.x + threadIdx.x;
  int k = gid >> 7;
  float n = *nsum;
  float sz = (out_en[k] + 1e-8f) / (n + 1e-8f * (float)N_TOKEN) * n;
  float4 w = reinterpret_cast<const float4*>(out_ew)[gid];
  float4 o;
  o.x = w.x / sz; o.y = w.y / sz; o.z = w.z / sz; o.w = w.w / sz;
  reinterpret_cast<float4*>(out_kw)[gid] = o;
}

// ---------- launcher ----------
extern "C" void kernel_launch(void* const* d_in, const int* in_sizes, int n_in,
                              void* d_out, int out_size, void* d_ws, size_t ws_size,
                              hipStream_t stream) {
  const float* x       = (const float*)d_in[0];
  const float* key_w   = (const float*)d_in[1];
  const float* value_w = (const float*)d_in[2];
  const float* ema_n   = (const float*)d_in[3];
  const float* ema_w   = (const float*)d_in[4];

  float* out_q  = (float*)d_out;
  float* out_en = out_q + 8388608;
  float* out_ew = out_en + N_TOKEN;
  float* out_kw = out_ew + 4194304;

  // ---- two-stage layout ----
  const size_t SLOTS_B = (size_t)T_TOKENS * NSLOT * 16;            // 1 MiB
  const size_t XP_B    = (size_t)T_TOKENS * KPM * 2;               // 32 MiB
  const size_t KP_B    = (size_t)N_TOKEN * KPM * 2;                // 16 MiB
  char* base = (char*)d_ws;
  float4* slots = (float4*)base;
  __bf16* xp2 = (__bf16*)(base + SLOTS_B);
  __bf16* kp2 = (__bf16*)(base + SLOTS_B + XP_B);
  char* tail  = base + SLOTS_B + XP_B + KP_B;
  float* h                  = (float*)(tail + 0);         // 32 KiB
  int*   idx                = (int*)(tail + 32768);       // 64 KiB
  unsigned int* tlist       = (unsigned int*)(tail + 98304);   // 64 KiB
  unsigned long long* rbest = (unsigned long long*)(tail + 163840);  // 128 KiB
  unsigned int* ucount      = (unsigned int*)(tail + 294912);  // 256 B
  float* nsum               = (float*)(tail + 295168);    // 256 B
  int* counts               = (int*)(tail + 295424);      // 32 KiB
  int* offs                 = (int*)(tail + 328192);      // 32 KiB
  int* cursor               = (int*)(tail + 360960);      // 32 KiB
  int* tok                  = (int*)(tail + 393728);      // 64 KiB
  const size_t ws_need2 = SLOTS_B + XP_B + KP_B + 459264;

  // ---- single-stage layout (fallback) ----
  unsigned long long* f_best = (unsigned long long*)d_ws;
  int*   f_idx  = (int*)((char*)d_ws + 131072);
  float* f_h    = (float*)((char*)d_ws + 196608);
  float* f_nsum = (float*)((char*)d_ws + 229376);
  __bf16* f_xp  = (__bf16*)((char*)d_ws + 262144);
  __bf16* f_kp  = (__bf16*)((char*)d_ws + 262144 + XP_B);
  const size_t ws_need1 = 262144 + XP_B + KP_B;

  if (ws_size >= ws_need2) {
    // ---------- two-stage path ----------
    k_pack_all<<<6146, 256, 0, stream>>>(x, key_w, ema_n, xp2, kp2, h, nsum,
                                         ucount, counts);
    k_mfma_top2<<<512, 256, 0, stream>>>(xp2, kp2, h, slots);
    k_top2_reduce<<<T_TOKENS / 64, 256, 0, stream>>>(slots, idx, tlist, ucount,
                                                     counts, rbest);
    {
      dim3 grid(N_TOKEN / BNr, 16);
      k_mfma_refine<<<grid, 256, 0, stream>>>(xp2, kp2, h, tlist, ucount, rbest);
    }
    k_finalize<<<T_TOKENS / 256, 256, 0, stream>>>(rbest, tlist, ucount, idx, counts);

    k_scan<<<1, 256, 0, stream>>>(counts, offs, cursor);
    k_place<<<T_TOKENS / 256, 256, 0, stream>>>(idx, cursor, tok);
    k_update<<<N_TOKEN / 4, 256, 0, stream>>>(x, ema_n, ema_w, value_w, counts,
                                              offs, tok, nsum,
                                              out_en, out_ew, out_kw, out_q);
  } else if (ws_size >= ws_need1) {
    // ---------- single-stage path ----------
    hipMemsetAsync(f_best, 0xFF, (size_t)T_TOKENS * 8, stream);
    k_pack_x<<<(T_TOKENS * (N_EMBED / 4)) / 256, 256, 0, stream>>>(x, f_xp);
    k_pack_k_norm<<<N_TOKEN / 4, 256, 0, stream>>>(key_w, f_kp, f_h);
    dim3 grid(N_TOKEN / BNr, T_TOKENS / BMr);
    k_mfma_argmin<<<grid, 256, 0, stream>>>(f_xp, f_kp, f_h, f_best);

    k_scaleN<<<N_TOKEN / 256, 256, 0, stream>>>(ema_n, out_en);
    k_extract_counts<<<T_TOKENS / 256, 256, 0, stream>>>(f_best, f_idx, out_en);
    k_scaleW<<<(N_TOKEN * (N_EMBED / 4)) / 256, 256, 0, stream>>>(ema_w, out_ew);
    k_quant_scatter<<<(T_TOKENS * (N_EMBED / 4)) / 256, 256, 0, stream>>>(
        x, value_w, f_idx, out_q, out_ew);
    k_sumn<<<1, 256, 0, stream>>>(out_en, f_nsum);
    k_keyw<<<(N_TOKEN * (N_EMBED / 4)) / 256, 256, 0, stream>>>(out_ew, out_en, f_nsum, out_kw);
  } else {
    // ---------- deep fallback: f32 vector GEMM ----------
    hipMemsetAsync(f_best, 0xFF, (size_t)T_TOKENS * 8, stream);
    k_hnorm<<<N_TOKEN / 4, 256, 0, stream>>>(key_w, f_h);
    dim3 grid(N_TOKEN / BK, T_TOKENS / BT);
    k_gemm_argmin<<<grid, 256, 0, stream>>>(x, key_w, f_h, f_best);

    k_scaleN<<<N_TOKEN / 256, 256, 0, stream>>>(ema_n, out_en);
    k_extract_counts<<<T_TOKENS / 256, 256, 0, stream>>>(f_best, f_idx, out_en);
    k_scaleW<<<(N_TOKEN * (N_EMBED / 4)) / 256, 256, 0, stream>>>(ema_w, out_ew);
    k_quant_scatter<<<(T_TOKENS * (N_EMBED / 4)) / 256, 256, 0, stream>>>(
        x, value_w, f_idx, out_q, out_ew);
    k_sumn<<<1, 256, 0, stream>>>(out_en, f_nsum);
    k_keyw<<<(N_TOKEN * (N_EMBED / 4)) / 256, 256, 0, stream>>>(out_ew, out_en, f_nsum, out_kw);
  }
}

// Round 17
// 354.752 us; speedup vs baseline: 1.0388x; 1.0388x over previous
//
#include <hip/hip_runtime.h>

#define N_TOKEN 8192
#define N_EMBED 512
#define T_TOKENS 16384
#define KP 1536       // logical packed K = 3 * 512
#define KPM 1024      // memory stride: [hi|lo] 2-segment rows
#define MARGIN 0.45f  // score-gap certainty threshold (~9 sigma of approx error)
#define NBG 8         // nb tiles per top2 block

typedef __bf16 bf16x8 __attribute__((ext_vector_type(8)));
typedef __bf16 bf16x4 __attribute__((ext_vector_type(4)));
typedef float f32x4 __attribute__((ext_vector_type(4)));

// ---------- helpers ----------
__device__ __forceinline__ unsigned int fkey(float f) {
  unsigned int u = __float_as_uint(f);
  return (u & 0x80000000u) ? ~u : (u | 0x80000000u);
}
__device__ __forceinline__ void gl2lds16(const void* gsrc, void* lds) {
  __builtin_amdgcn_global_load_lds(
      (const __attribute__((address_space(1))) unsigned int*)gsrc,
      (__attribute__((address_space(3))) unsigned int*)lds, 16, 0, 0);
}
__device__ __forceinline__ unsigned long long umin64(unsigned long long a,
                                                     unsigned long long b) {
  return a < b ? a : b;
}

// ---------- pack bodies: f32 -> [hi|lo] bf16 (both x and k) ----------
__device__ __forceinline__ void pack_hl_body(const float* __restrict__ src,
                                             __bf16* __restrict__ dstbuf, int gid) {
  int t = gid >> 7, d4 = gid & 127;
  float4 v = reinterpret_cast<const float4*>(src)[gid];
  bf16x4 hi, lo;
  hi[0] = (__bf16)v.x; hi[1] = (__bf16)v.y; hi[2] = (__bf16)v.z; hi[3] = (__bf16)v.w;
  lo[0] = (__bf16)(v.x - (float)hi[0]);
  lo[1] = (__bf16)(v.y - (float)hi[1]);
  lo[2] = (__bf16)(v.z - (float)hi[2]);
  lo[3] = (__bf16)(v.w - (float)hi[3]);
  __bf16* row = dstbuf + (size_t)t * KPM + d4 * 4;
  *(bf16x4*)(row)       = hi;
  *(bf16x4*)(row + 512) = lo;
}

__device__ __forceinline__ void pack_k_body(const float* __restrict__ kw,
                                            __bf16* __restrict__ kp,
                                            float* __restrict__ h,
                                            int blk, int tid) {
  int row = blk * 4 + (tid >> 6);
  int lane = tid & 63;
  const float4* src = reinterpret_cast<const float4*>(kw + (size_t)row * N_EMBED);
  __bf16* dst = kp + (size_t)row * KPM;
  float s = 0.f;
  #pragma unroll
  for (int c = 0; c < 2; ++c) {
    int f4 = lane + c * 64;
    float4 v = src[f4];
    s += v.x*v.x + v.y*v.y + v.z*v.z + v.w*v.w;
    bf16x4 hi, lo;
    hi[0] = (__bf16)v.x; hi[1] = (__bf16)v.y; hi[2] = (__bf16)v.z; hi[3] = (__bf16)v.w;
    lo[0] = (__bf16)(v.x - (float)hi[0]);
    lo[1] = (__bf16)(v.y - (float)hi[1]);
    lo[2] = (__bf16)(v.z - (float)hi[2]);
    lo[3] = (__bf16)(v.w - (float)hi[3]);
    *(bf16x4*)(dst + f4 * 4)       = hi;
    *(bf16x4*)(dst + 512 + f4 * 4) = lo;
  }
  #pragma unroll
  for (int off = 32; off; off >>= 1) s += __shfl_down(s, off);
  if (lane == 0) h[row] = 0.5f * s;
}

// ---------- fused prep: pack_x | pack_k+norm | sum(ema_n)+init ----------
__global__ void k_pack_all(const float* __restrict__ x, const float* __restrict__ kw,
                           const float* __restrict__ ema_n,
                           __bf16* __restrict__ xp, __bf16* __restrict__ kp,
                           float* __restrict__ h, float* __restrict__ nsum,
                           unsigned int* __restrict__ ucount, int* __restrict__ counts) {
  int b = blockIdx.x;
  if (b < 8192) {
    pack_hl_body(x, xp, b * 256 + threadIdx.x);
  } else if (b < 10240) {
    pack_k_body(kw, kp, h, b - 8192, threadIdx.x);
  } else if (b == 10240) {
    __shared__ float sm[256];
    float s = 0.f;
    for (int i = threadIdx.x; i < N_TOKEN; i += 256) s += ema_n[i];
    sm[threadIdx.x] = s;
    __syncthreads();
    for (int off = 128; off; off >>= 1) {
      if (threadIdx.x < off) sm[threadIdx.x] += sm[threadIdx.x + off];
      __syncthreads();
    }
    if (threadIdx.x == 0) { *nsum = sm[0]; *ucount = 0u; }
  } else {
    for (int i = threadIdx.x; i < N_TOKEN; i += 256) counts[i] = 0;
  }
}

// ---------- standalone packs (fallback paths) ----------
__global__ void k_pack_x(const float* __restrict__ x, __bf16* __restrict__ xp) {
  pack_hl_body(x, xp, blockIdx.x * blockDim.x + threadIdx.x);
}
__global__ void k_pack_k_norm(const float* __restrict__ kw, __bf16* __restrict__ kp,
                              float* __restrict__ h) {
  pack_k_body(kw, kp, h, blockIdx.x, threadIdx.x);
}

// ---------- norms only (deep fallback) ----------
__global__ void k_hnorm(const float* __restrict__ key_w, float* __restrict__ h) {
  int code = blockIdx.x * 4 + (threadIdx.x >> 6);
  int lane = threadIdx.x & 63;
  const float4* row = reinterpret_cast<const float4*>(key_w + (size_t)code * N_EMBED);
  float s = 0.f;
  float4 v0 = row[lane];
  float4 v1 = row[lane + 64];
  s += v0.x*v0.x + v0.y*v0.y + v0.z*v0.z + v0.w*v0.w;
  s += v1.x*v1.x + v1.y*v1.y + v1.z*v1.z + v1.w*v1.w;
  #pragma unroll
  for (int off = 32; off; off >>= 1) s += __shfl_down(s, off);
  if (lane == 0) h[code] = 0.5f * s;
}

#define BMr 128
#define BNr 128
#define BKe 64   // refine K-step (128 B rows)

// ---------- PASS 1: K=512 hi*hi GEMM; BK=128 (4 K-steps); 8 nb tiles/block ---
// XCD-locality swizzle: each XCD owns a 16-mb A-band reused across all B tiles.
// __launch_bounds__(256, 2): pin VGPR <= 128 so 2 blocks/CU stay resident.
__global__ __launch_bounds__(256, 2) void k_mfma_top2(
    const __bf16* __restrict__ xp, const __bf16* __restrict__ kp,
    const float* __restrict__ h, float4* __restrict__ slots) {
  __shared__ __bf16 AS[128 * 128];  // 32 KB, 256 B rows
  __shared__ __bf16 BS[128 * 128];  // 32 KB

  const int b = blockIdx.x;
  const int xcd = b & 7, chunk = b >> 3;
  const int mb = xcd * 16 + (chunk & 15);
  const int nbg = chunk >> 4;
  const int m0 = mb * BMr;
  const int tid = threadIdx.x;
  const int lane = tid & 63;
  const int wid = tid >> 6;
  const int wm = wid * 32;           // 4 waves x 32 rows
  const int soff = tid * 16;
  const int rgrp = lane >> 4;
  const int cidx = lane & 15;

  float rs1[8], rs2[8];
  int rc1[8];
  #pragma unroll
  for (int u = 0; u < 8; ++u) { rs1[u] = 3.4e38f; rs2[u] = 3.4e38f; rc1[u] = 0; }

  for (int q = 0; q < NBG; ++q) {
    const int n0 = (nbg * NBG + q) * BNr;
    f32x4 acc[2][8] = {};

    for (int ks = 0; ks < 512; ks += 128) {   // hi columns, 256 B rows
      __syncthreads();
      #pragma unroll
      for (int i = 0; i < 8; ++i) {
        int off = i * 4096 + soff;
        int row = off >> 8;
        int inner = (off & 255) ^ ((row & 7) << 4);
        gl2lds16(xp + (size_t)(m0 + row) * KPM + ks + (inner >> 1), (char*)AS + off);
        gl2lds16(kp + (size_t)(n0 + row) * KPM + ks + (inner >> 1), (char*)BS + off);
      }
      asm volatile("s_waitcnt vmcnt(0)" ::: "memory");
      __syncthreads();

      #pragma unroll
      for (int kk = 0; kk < 4; ++kk) {
        const int cbyte = kk * 64 + (lane >> 4) * 16;
        bf16x8 af[2], bb[8];
        #pragma unroll
        for (int i = 0; i < 2; ++i) {
          int arow = wm + i * 16 + (lane & 15);
          af[i] = *(const bf16x8*)((const char*)AS + arow * 256 + (cbyte ^ ((arow & 7) << 4)));
        }
        #pragma unroll
        for (int j = 0; j < 8; ++j) {
          int brow = j * 16 + (lane & 15);
          bb[j] = *(const bf16x8*)((const char*)BS + brow * 256 + (cbyte ^ ((brow & 7) << 4)));
        }
        #pragma unroll
        for (int i = 0; i < 2; ++i)
          #pragma unroll
          for (int j = 0; j < 8; ++j)
            acc[i][j] = __builtin_amdgcn_mfma_f32_16x16x32_bf16(af[i], bb[j], acc[i][j], 0, 0, 0);
      }
    }

    // insert this tile's 8 scores per output row into running top-2
    #pragma unroll
    for (int i = 0; i < 2; ++i) {
      #pragma unroll
      for (int r = 0; r < 4; ++r) {
        const int u = i * 4 + r;
        float s1 = rs1[u], s2 = rs2[u];
        int c1 = rc1[u];
        #pragma unroll
        for (int j = 0; j < 8; ++j) {
          int kk = n0 + j * 16 + cidx;
          float sc = h[kk] - acc[i][j][r];
          if (sc < s1) { s2 = s1; s1 = sc; c1 = kk; }
          else s2 = fminf(s2, sc);
        }
        rs1[u] = s1; rs2[u] = s2; rc1[u] = c1;
      }
    }
  }

  // one butterfly per output row; slot per (row, nbg)
  #pragma unroll
  for (int u = 0; u < 8; ++u) {
    float s1 = rs1[u], s2 = rs2[u];
    int c1 = rc1[u];
    #pragma unroll
    for (int msk = 1; msk < 16; msk <<= 1) {
      float o1 = __shfl_xor(s1, msk);
      float o2 = __shfl_xor(s2, msk);
      int   oc = __shfl_xor(c1, msk);
      float ns2 = fminf(fminf(s2, o2), fmaxf(s1, o1));
      bool take = o1 < s1;
      s1 = take ? o1 : s1;
      c1 = take ? oc : c1;
      s2 = ns2;
    }
    if (cidx == 0) {
      int row = m0 + wm + (u >> 2) * 16 + rgrp * 4 + (u & 3);
      float4 p;
      p.x = s1; p.y = s2; p.z = __int_as_float(c1); p.w = 0.f;
      slots[(size_t)row * NBG + nbg] = p;
    }
  }
}

// ---------- reduce: global top-2 (8 slots) -> certain idx (+count) or list ---
__global__ void k_top2_reduce(const float4* __restrict__ slots,
                              int* __restrict__ idx, unsigned int* __restrict__ tlist,
                              unsigned int* __restrict__ ucount,
                              int* __restrict__ counts,
                              unsigned long long* __restrict__ rbest) {
  int tid = threadIdx.x;
  int lane = tid & 63, wid = tid >> 6;
  int row = blockIdx.x * 32 + wid * 8 + (lane >> 3);
  int slot = lane & 7;
  float4 a = slots[(size_t)row * NBG + slot];
  float s1 = a.x, s2 = a.y;
  int c1 = __float_as_int(a.z);
  #pragma unroll
  for (int msk = 1; msk < 8; msk <<= 1) {
    float o1 = __shfl_xor(s1, msk);
    float o2 = __shfl_xor(s2, msk);
    int   oc = __shfl_xor(c1, msk);
    float ns2 = fminf(fminf(s2, o2), fmaxf(s1, o1));
    bool take = o1 < s1;
    s1 = take ? o1 : s1;
    c1 = take ? oc : c1;
    s2 = ns2;
  }
  if (slot == 0) {
    if (s2 - s1 >= MARGIN) {
      idx[row] = c1;
      atomicAdd(&counts[c1], 1);
    } else {
      unsigned int p = atomicAdd(ucount, 1u);
      tlist[p] = (unsigned int)row;
      rbest[p] = ~0ull;   // init for refine's atomicMin
    }
  }
}

// ---------- REFINE: 3-term K=1536 exact-class GEMM over uncertain tokens ----
// Memory is [hi|lo] (KPM=1024); logical A = [hi|hi|lo], B = [hi|lo|hi] via
// wave-uniform ks remap: ksA = ks<512 ? ks : ks-512; ksB = ks<1024 ? ks : ks-1024.
__global__ __launch_bounds__(256) void k_mfma_refine(
    const __bf16* __restrict__ xp, const __bf16* __restrict__ kp,
    const float* __restrict__ h, const unsigned int* __restrict__ tlist,
    const unsigned int* __restrict__ ucount, unsigned long long* __restrict__ rbest) {
  const unsigned int uc = *ucount;
  const int nb = blockIdx.x, mb = blockIdx.y;
  const int m0 = mb * BMr;
  if ((unsigned int)m0 >= uc) return;

  __shared__ __bf16 AS[BMr * BKe];
  __shared__ __bf16 BS[BNr * BKe];

  const int n0 = nb * BNr;
  const int tid = threadIdx.x;
  const int lane = tid & 63;
  const int wid = tid >> 6;
  const int wm = (wid >> 1) * 64, wn = (wid & 1) * 64;

  const int r0 = tid >> 3;  // 0..31
  size_t abase[4];
  #pragma unroll
  for (int i = 0; i < 4; ++i) {
    int p = m0 + r0 + 32 * i;
    int pc = p < (int)uc ? p : (int)uc - 1;
    abase[i] = (size_t)tlist[pc] * KPM;
  }

  f32x4 acc[4][4] = {};
  const int soff = tid * 16;
  const int innerC = (soff & 127) ^ ((r0 & 7) << 4);

  for (int ks = 0; ks < KP; ks += BKe) {
    const int ksA = ks < 512 ? ks : ks - 512;     // [hi|hi|lo]
    const int ksB = ks < 1024 ? ks : ks - 1024;   // [hi|lo|hi]
    __syncthreads();
    #pragma unroll
    for (int i = 0; i < 4; ++i) {
      int off = i * 4096 + soff;
      int brow = (off >> 7);
      gl2lds16(xp + abase[i] + ksA + (innerC >> 1), (char*)AS + off);
      int binner = (off & 127) ^ ((brow & 7) << 4);
      gl2lds16(kp + (size_t)(n0 + brow) * KPM + ksB + (binner >> 1), (char*)BS + off);
    }
    asm volatile("s_waitcnt vmcnt(0)" ::: "memory");
    __syncthreads();

    #pragma unroll
    for (int kk = 0; kk < 2; ++kk) {
      const int cbyte = kk * 64 + (lane >> 4) * 16;
      bf16x8 af[4], bb[4];
      #pragma unroll
      for (int i = 0; i < 4; ++i) {
        int arow = wm + i * 16 + (lane & 15);
        af[i] = *(const bf16x8*)((const char*)AS + arow * 128 + (cbyte ^ ((arow & 7) << 4)));
        int brow = wn + i * 16 + (lane & 15);
        bb[i] = *(const bf16x8*)((const char*)BS + brow * 128 + (cbyte ^ ((brow & 7) << 4)));
      }
      #pragma unroll
      for (int i = 0; i < 4; ++i)
        #pragma unroll
        for (int j = 0; j < 4; ++j)
          acc[i][j] = __builtin_amdgcn_mfma_f32_16x16x32_bf16(af[i], bb[j], acc[i][j], 0, 0, 0);
    }
  }

  const int rgrp = lane >> 4;
  const int cidx = lane & 15;
  #pragma unroll
  for (int i = 0; i < 4; ++i) {
    #pragma unroll
    for (int r = 0; r < 4; ++r) {
      unsigned long long m = ~0ull;
      #pragma unroll
      for (int j = 0; j < 4; ++j) {
        int kk = n0 + wn + j * 16 + cidx;
        float score = h[kk] - acc[i][j][r];
        unsigned long long cand =
            ((unsigned long long)fkey(score) << 32) | (unsigned int)kk;
        m = umin64(m, cand);
      }
      #pragma unroll
      for (int msk = 1; msk < 16; msk <<= 1) m = umin64(m, __shfl_xor(m, msk));
      if (cidx == 0) {
        int p = m0 + wm + i * 16 + rgrp * 4 + r;
        if ((unsigned int)p < uc) atomicMin(&rbest[p], m);
      }
    }
  }
}

// ---------- finalize: uncertain rows get refined index (+count) ----------
__global__ void k_finalize(const unsigned long long* __restrict__ rbest,
                           const unsigned int* __restrict__ tlist,
                           const unsigned int* __restrict__ ucount,
                           int* __restrict__ idx, int* __restrict__ counts) {
  unsigned int p = blockIdx.x * 256 + threadIdx.x;
  if (p < *ucount) {
    int k = (int)(unsigned int)(rbest[p] & 0xffffffffull);
    idx[tlist[p]] = k;
    atomicAdd(&counts[k], 1);
  }
}

// ---------- counting-sort CSR + fused EMA update ----------
__global__ void k_scan(const int* __restrict__ counts, int* __restrict__ offs,
                       int* __restrict__ cursor) {
  __shared__ int sa[256], sb[256];
  int tid = threadIdx.x;
  int base = tid * 32;
  int loc[32]; int s = 0;
  #pragma unroll
  for (int e = 0; e < 32; ++e) { loc[e] = s; s += counts[base + e]; }
  sa[tid] = s;
  __syncthreads();
  int* src = sa; int* dst = sb;
  for (int d = 1; d < 256; d <<= 1) {
    int v = src[tid] + (tid >= d ? src[tid - d] : 0);
    dst[tid] = v;
    __syncthreads();
    int* tmp = src; src = dst; dst = tmp;
  }
  int excl = src[tid] - s;
  #pragma unroll
  for (int e = 0; e < 32; ++e) {
    int o = excl + loc[e];
    offs[base + e] = o;
    cursor[base + e] = o;
  }
}

__global__ void k_place(const int* __restrict__ idx, int* __restrict__ cursor,
                        int* __restrict__ tok) {
  int t = blockIdx.x * 256 + threadIdx.x;
  if (t < T_TOKENS) {
    int p = atomicAdd(&cursor[idx[t]], 1);
    tok[p] = t;
  }
}

// one wave per code: en; ew = 0.99*ema_w + 0.005*sum(x[tok]); kw = ew/sz;
// and quantized[t] = x[t] + value_w[k] for each token of this code (fused).
__global__ void k_update(const float* __restrict__ x, const float* __restrict__ ema_n,
                         const float* __restrict__ ema_w, const float* __restrict__ value_w,
                         const int* __restrict__ counts,
                         const int* __restrict__ offs, const int* __restrict__ tok,
                         const float* __restrict__ nsum,
                         float* __restrict__ out_en, float* __restrict__ out_ew,
                         float* __restrict__ out_kw, float* __restrict__ out_q) {
  int k = blockIdx.x * 4 + (threadIdx.x >> 6);
  int lane = threadIdx.x & 63;
  int cnt = counts[k];
  int off = offs[k];
  float en = 0.99f * ema_n[k] + 0.005f * (float)cnt;
  if (lane == 0) out_en[k] = en;
  float n = 0.99f * (*nsum) + 81.92f;   // 0.005 * 16384
  float sz = (en + 1e-8f) / (n + 1e-8f * (float)N_TOKEN) * n;

  const float4* er = reinterpret_cast<const float4*>(ema_w + (size_t)k * N_EMBED);
  float4 e0 = er[lane], e1 = er[lane + 64];
  const float4* vr = reinterpret_cast<const float4*>(value_w + (size_t)k * N_EMBED);
  float4 v0 = vr[lane], v1 = vr[lane + 64];
  float4 s0 = {0.f, 0.f, 0.f, 0.f}, s1v = {0.f, 0.f, 0.f, 0.f};
  for (int q = 0; q < cnt; ++q) {
    int t = tok[off + q];
    const float4* xr = reinterpret_cast<const float4*>(x + (size_t)t * N_EMBED);
    float4 a = xr[lane], b = xr[lane + 64];
    s0.x += a.x; s0.y += a.y; s0.z += a.z; s0.w += a.w;
    s1v.x += b.x; s1v.y += b.y; s1v.z += b.z; s1v.w += b.w;
    float4 qa, qb;
    qa.x = a.x + v0.x; qa.y = a.y + v0.y; qa.z = a.z + v0.z; qa.w = a.w + v0.w;
    qb.x = b.x + v1.x; qb.y = b.y + v1.y; qb.z = b.z + v1.z; qb.w = b.w + v1.w;
    float4* oq = reinterpret_cast<float4*>(out_q + (size_t)t * N_EMBED);
    oq[lane] = qa; oq[lane + 64] = qb;
  }
  float4 w0, w1;
  w0.x = 0.99f * e0.x + 0.005f * s0.x;  w0.y = 0.99f * e0.y + 0.005f * s0.y;
  w0.z = 0.99f * e0.z + 0.005f * s0.z;  w0.w = 0.99f * e0.w + 0.005f * s0.w;
  w1.x = 0.99f * e1.x + 0.005f * s1v.x; w1.y = 0.99f * e1.y + 0.005f * s1v.y;
  w1.z = 0.99f * e1.z + 0.005f * s1v.z; w1.w = 0.99f * e1.w + 0.005f * s1v.w;
  float4* ow = reinterpret_cast<float4*>(out_ew + (size_t)k * N_EMBED);
  ow[lane] = w0; ow[lane + 64] = w1;
  float4 q0, q1;
  q0.x = w0.x / sz; q0.y = w0.y / sz; q0.z = w0.z / sz; q0.w = w0.w / sz;
  q1.x = w1.x / sz; q1.y = w1.y / sz; q1.z = w1.z / sz; q1.w = w1.w / sz;
  float4* okw = reinterpret_cast<float4*>(out_kw + (size_t)k * N_EMBED);
  okw[lane] = q0; okw[lane + 64] = q1;
}

// ---------- quantized = x + value_w[idx] (fallback paths only) ----------
__global__ void k_quant(const float* __restrict__ x, const float* __restrict__ value_w,
                        const int* __restrict__ idx, float* __restrict__ q) {
  int gid = blockIdx.x * blockDim.x + threadIdx.x;
  int t = gid >> 7, d4 = gid & 127;
  float4 xv = reinterpret_cast<const float4*>(x)[gid];
  float4 v = reinterpret_cast<const float4*>(value_w + (size_t)idx[t] * N_EMBED)[d4];
  float4 o;
  o.x = xv.x + v.x; o.y = xv.y + v.y; o.z = xv.z + v.z; o.w = xv.w + v.w;
  reinterpret_cast<float4*>(q)[gid] = o;
}

// ---------- single-stage MFMA GEMM + argmin (ws fallback; [hi|lo] remap) -----
__global__ __launch_bounds__(256) void k_mfma_argmin(
    const __bf16* __restrict__ xp, const __bf16* __restrict__ kp,
    const float* __restrict__ h, unsigned long long* __restrict__ best) {
  __shared__ __bf16 AS[BMr * BKe];
  __shared__ __bf16 BS[BNr * BKe];
  const int nb = blockIdx.x, mb = blockIdx.y;
  const int m0 = mb * BMr, n0 = nb * BNr;
  const int tid = threadIdx.x;
  const int lane = tid & 63;
  const int wid = tid >> 6;
  const int wm = (wid >> 1) * 64, wn = (wid & 1) * 64;
  f32x4 acc[4][4] = {};
  const int soff = tid * 16;
  for (int ks = 0; ks < KP; ks += BKe) {
    const int ksA = ks < 512 ? ks : ks - 512;
    const int ksB = ks < 1024 ? ks : ks - 1024;
    __syncthreads();
    #pragma unroll
    for (int i = 0; i < 4; ++i) {
      int off = i * 4096 + soff;
      int row = off >> 7;
      int inner = (off & 127) ^ ((row & 7) << 4);
      gl2lds16(xp + (size_t)(m0 + row) * KPM + ksA + (inner >> 1), (char*)AS + off);
      gl2lds16(kp + (size_t)(n0 + row) * KPM + ksB + (inner >> 1), (char*)BS + off);
    }
    asm volatile("s_waitcnt vmcnt(0)" ::: "memory");
    __syncthreads();
    #pragma unroll
    for (int kk = 0; kk < 2; ++kk) {
      const int cbyte = kk * 64 + (lane >> 4) * 16;
      bf16x8 af[4], bb[4];
      #pragma unroll
      for (int i = 0; i < 4; ++i) {
        int arow = wm + i * 16 + (lane & 15);
        af[i] = *(const bf16x8*)((const char*)AS + arow * 128 + (cbyte ^ ((arow & 7) << 4)));
        int brow = wn + i * 16 + (lane & 15);
        bb[i] = *(const bf16x8*)((const char*)BS + brow * 128 + (cbyte ^ ((brow & 7) << 4)));
      }
      #pragma unroll
      for (int i = 0; i < 4; ++i)
        #pragma unroll
        for (int j = 0; j < 4; ++j)
          acc[i][j] = __builtin_amdgcn_mfma_f32_16x16x32_bf16(af[i], bb[j], acc[i][j], 0, 0, 0);
    }
  }
  const int rgrp = lane >> 4;
  const int cidx = lane & 15;
  #pragma unroll
  for (int i = 0; i < 4; ++i) {
    #pragma unroll
    for (int r = 0; r < 4; ++r) {
      unsigned long long m = ~0ull;
      #pragma unroll
      for (int j = 0; j < 4; ++j) {
        int kk = n0 + wn + j * 16 + cidx;
        float score = h[kk] - acc[i][j][r];
        unsigned long long cand =
            ((unsigned long long)fkey(score) << 32) | (unsigned int)kk;
        m = umin64(m, cand);
      }
      #pragma unroll
      for (int msk = 1; msk < 16; msk <<= 1) m = umin64(m, __shfl_xor(m, msk));
      if (cidx == 0) {
        int row = m0 + wm + i * 16 + rgrp * 4 + r;
        atomicMin(&best[row], m);
      }
    }
  }
}

// ---------- f32 fallback GEMM+argmin ----------
#define BT 128
#define BK 128
#define DC 32
__global__ __launch_bounds__(256, 2) void k_gemm_argmin(
    const float* __restrict__ x, const float* __restrict__ key_w,
    const float* __restrict__ h, unsigned long long* __restrict__ best) {
  __shared__ float4 XS[BT * 8];
  __shared__ float4 KS[BK * 8];
  const int kb = blockIdx.x, tb = blockIdx.y;
  const int t0 = tb * BT, k0 = kb * BK;
  const int tid = threadIdx.x;
  const int tx = tid & 15;
  const int tyg = tid >> 4;
  float acc[8][8];
  #pragma unroll
  for (int i = 0; i < 8; ++i)
    #pragma unroll
    for (int j = 0; j < 8; ++j) acc[i][j] = 0.f;
  for (int dc = 0; dc < N_EMBED; dc += DC) {
    __syncthreads();
    #pragma unroll
    for (int ld = 0; ld < 4; ++ld) {
      int li = ld * 256 + tid;
      int row = li >> 3, c4 = li & 7;
      XS[row * 8 + (c4 ^ (row & 7))] =
          *reinterpret_cast<const float4*>(x + (size_t)(t0 + row) * N_EMBED + dc + c4 * 4);
      KS[row * 8 + (c4 ^ (row & 7))] =
          *reinterpret_cast<const float4*>(key_w + (size_t)(k0 + row) * N_EMBED + dc + c4 * 4);
    }
    __syncthreads();
    #pragma unroll
    for (int d4 = 0; d4 < 8; ++d4) {
      float4 a[8], b[8];
      #pragma unroll
      for (int j = 0; j < 8; ++j) {
        a[j] = XS[(tyg + 16 * j) * 8 + (d4 ^ (tyg & 7))];
        b[j] = KS[(tx  + 16 * j) * 8 + (d4 ^ (tx  & 7))];
      }
      #pragma unroll
      for (int i = 0; i < 8; ++i) {
        float4 av = a[i];
        #pragma unroll
        for (int j = 0; j < 8; ++j) {
          float4 bv = b[j];
          acc[i][j] = fmaf(av.x, bv.x, fmaf(av.y, bv.y,
                      fmaf(av.z, bv.z, fmaf(av.w, bv.w, acc[i][j]))));
        }
      }
    }
  }
  #pragma unroll
  for (int i = 0; i < 8; ++i) {
    unsigned long long m = ~0ull;
    #pragma unroll
    for (int j = 0; j < 8; ++j) {
      int kk = k0 + tx + 16 * j;
      float score = h[kk] - acc[i][j];
      unsigned long long cand =
          ((unsigned long long)fkey(score) << 32) | (unsigned int)kk;
      m = umin64(m, cand);
    }
    #pragma unroll
    for (int mask = 1; mask < 16; mask <<= 1) m = umin64(m, __shfl_xor(m, mask));
    if (tx == 0) atomicMin(&best[t0 + tyg + 16 * i], m);
  }
}

// ---------- legacy aux (fallback paths) ----------
__global__ void k_extract_counts(const unsigned long long* __restrict__ best,
                                 int* __restrict__ idx, float* __restrict__ out_en) {
  int t = blockIdx.x * blockDim.x + threadIdx.x;
  if (t < T_TOKENS) {
    int k = (int)(unsigned int)(best[t] & 0xffffffffull);
    idx[t] = k;
    atomicAdd(&out_en[k], 0.005f);
  }
}
__global__ void k_quant_scatter(const float* __restrict__ x,
                                const float* __restrict__ value_w,
                                const int* __restrict__ idx,
                                float* __restrict__ q, float* __restrict__ out_ew) {
  int gid = blockIdx.x * blockDim.x + threadIdx.x;
  int t = gid >> 7, d4 = gid & 127;
  float4 xv = reinterpret_cast<const float4*>(x)[gid];
  int k = idx[t];
  float4 v = reinterpret_cast<const float4*>(value_w + (size_t)k * N_EMBED)[d4];
  float4 o;
  o.x = xv.x + v.x; o.y = xv.y + v.y; o.z = xv.z + v.z; o.w = xv.w + v.w;
  reinterpret_cast<float4*>(q)[gid] = o;
  const float c = 0.005f;
  float* dst = out_ew + (size_t)k * N_EMBED + d4 * 4;
  atomicAdd(dst + 0, c * xv.x);
  atomicAdd(dst + 1, c * xv.y);
  atomicAdd(dst + 2, c * xv.z);
  atomicAdd(dst + 3, c * xv.w);
}
__global__ void k_scaleN(const float* __restrict__ ema_n, float* __restrict__ out_en) {
  int k = blockIdx.x * blockDim.x + threadIdx.x;
  if (k < N_TOKEN) out_en[k] = 0.99f * ema_n[k];
}
__global__ void k_scaleW(const float* __restrict__ ema_w, float* __restrict__ out_ew) {
  int gid = blockIdx.x * blockDim.x + threadIdx.x;
  float4 v = reinterpret_cast<const float4*>(ema_w)[gid];
  float4 o;
  o.x = 0.99f * v.x; o.y = 0.99f * v.y; o.z = 0.99f * v.z; o.w = 0.99f * v.w;
  reinterpret_cast<float4*>(out_ew)[gid] = o;
}
__global__ void k_sumn(const float* __restrict__ en, float* __restrict__ nsum) {
  __shared__ float sm[256];
  float s = 0.f;
  for (int i = threadIdx.x; i < N_TOKEN; i += 256) s += en[i];
  sm[threadIdx.x] = s;
  __syncthreads();
  for (int off = 128; off; off >>= 1) {
    if (threadIdx.x < off) sm[threadIdx.x] += sm[threadIdx.x + off];
    __syncthreads();
  }
  if (threadIdx.x == 0) *nsum = sm[0];
}
__global__ void k_keyw(const float* __restrict__ out_ew, const float* __restrict__ out_en,
                       const float* __restrict__ nsum, float* __restrict__ out_kw) {
  int gid = blockIdx.x * blockDim.x + threadIdx.x;
  int k = gid >> 7;
  float n = *nsum;
  float sz = (out_en[k] + 1e-8f) / (n + 1e-8f * (float)N_TOKEN) * n;
  float4 w = reinterpret_cast<const float4*>(out_ew)[gid];
  float4 o;
  o.x = w.x / sz; o.y = w.y / sz; o.z = w.z / sz; o.w = w.w / sz;
  reinterpret_cast<float4*>(out_kw)[gid] = o;
}

// ---------- launcher ----------
extern "C" void kernel_launch(void* const* d_in, const int* in_sizes, int n_in,
                              void* d_out, int out_size, void* d_ws, size_t ws_size,
                              hipStream_t stream) {
  const float* x       = (const float*)d_in[0];
  const float* key_w   = (const float*)d_in[1];
  const float* value_w = (const float*)d_in[2];
  const float* ema_n   = (const float*)d_in[3];
  const float* ema_w   = (const float*)d_in[4];

  float* out_q  = (float*)d_out;
  float* out_en = out_q + 8388608;
  float* out_ew = out_en + N_TOKEN;
  float* out_kw = out_ew + 4194304;

  // ---- two-stage layout ----
  const size_t SLOTS_B = (size_t)T_TOKENS * NBG * 16;              // 2 MiB
  const size_t XP_B    = (size_t)T_TOKENS * KPM * 2;               // 32 MiB
  const size_t KP_B    = (size_t)N_TOKEN * KPM * 2;                // 16 MiB
  char* base = (char*)d_ws;
  float4* slots = (float4*)base;
  __bf16* xp2 = (__bf16*)(base + SLOTS_B);
  __bf16* kp2 = (__bf16*)(base + SLOTS_B + XP_B);
  char* tail  = base + SLOTS_B + XP_B + KP_B;
  float* h                  = (float*)(tail + 0);         // 32 KiB
  int*   idx                = (int*)(tail + 32768);       // 64 KiB
  unsigned int* tlist       = (unsigned int*)(tail + 98304);   // 64 KiB
  unsigned long long* rbest = (unsigned long long*)(tail + 163840);  // 128 KiB
  unsigned int* ucount      = (unsigned int*)(tail + 294912);  // 256 B
  float* nsum               = (float*)(tail + 295168);    // 256 B
  int* counts               = (int*)(tail + 295424);      // 32 KiB
  int* offs                 = (int*)(tail + 328192);      // 32 KiB
  int* cursor               = (int*)(tail + 360960);      // 32 KiB
  int* tok                  = (int*)(tail + 393728);      // 64 KiB
  const size_t ws_need2 = SLOTS_B + XP_B + KP_B + 459264;

  // ---- single-stage layout (fallback) ----
  unsigned long long* f_best = (unsigned long long*)d_ws;
  int*   f_idx  = (int*)((char*)d_ws + 131072);
  float* f_h    = (float*)((char*)d_ws + 196608);
  float* f_nsum = (float*)((char*)d_ws + 229376);
  __bf16* f_xp  = (__bf16*)((char*)d_ws + 262144);
  __bf16* f_kp  = (__bf16*)((char*)d_ws + 262144 + XP_B);
  const size_t ws_need1 = 262144 + XP_B + KP_B;

  if (ws_size >= ws_need2) {
    // ---------- two-stage path ----------
    k_pack_all<<<10242, 256, 0, stream>>>(x, key_w, ema_n, xp2, kp2, h, nsum,
                                          ucount, counts);
    k_mfma_top2<<<1024, 256, 0, stream>>>(xp2, kp2, h, slots);
    k_top2_reduce<<<T_TOKENS / 32, 256, 0, stream>>>(slots, idx, tlist, ucount,
                                                     counts, rbest);
    {
      dim3 grid(N_TOKEN / BNr, T_TOKENS / BMr);
      k_mfma_refine<<<grid, 256, 0, stream>>>(xp2, kp2, h, tlist, ucount, rbest);
    }
    k_finalize<<<T_TOKENS / 256, 256, 0, stream>>>(rbest, tlist, ucount, idx, counts);

    k_scan<<<1, 256, 0, stream>>>(counts, offs, cursor);
    k_place<<<T_TOKENS / 256, 256, 0, stream>>>(idx, cursor, tok);
    k_update<<<N_TOKEN / 4, 256, 0, stream>>>(x, ema_n, ema_w, value_w, counts,
                                              offs, tok, nsum,
                                              out_en, out_ew, out_kw, out_q);
  } else if (ws_size >= ws_need1) {
    // ---------- single-stage path ----------
    hipMemsetAsync(f_best, 0xFF, (size_t)T_TOKENS * 8, stream);
    k_pack_x<<<(T_TOKENS * (N_EMBED / 4)) / 256, 256, 0, stream>>>(x, f_xp);
    k_pack_k_norm<<<N_TOKEN / 4, 256, 0, stream>>>(key_w, f_kp, f_h);
    dim3 grid(N_TOKEN / BNr, T_TOKENS / BMr);
    k_mfma_argmin<<<grid, 256, 0, stream>>>(f_xp, f_kp, f_h, f_best);

    k_scaleN<<<N_TOKEN / 256, 256, 0, stream>>>(ema_n, out_en);
    k_extract_counts<<<T_TOKENS / 256, 256, 0, stream>>>(f_best, f_idx, out_en);
    k_scaleW<<<(N_TOKEN * (N_EMBED / 4)) / 256, 256, 0, stream>>>(ema_w, out_ew);
    k_quant_scatter<<<(T_TOKENS * (N_EMBED / 4)) / 256, 256, 0, stream>>>(
        x, value_w, f_idx, out_q, out_ew);
    k_sumn<<<1, 256, 0, stream>>>(out_en, f_nsum);
    k_keyw<<<(N_TOKEN * (N_EMBED / 4)) / 256, 256, 0, stream>>>(out_ew, out_en, f_nsum, out_kw);
  } else {
    // ---------- deep fallback: f32 vector GEMM ----------
    hipMemsetAsync(f_best, 0xFF, (size_t)T_TOKENS * 8, stream);
    k_hnorm<<<N_TOKEN / 4, 256, 0, stream>>>(key_w, f_h);
    dim3 grid(N_TOKEN / BK, T_TOKENS / BT);
    k_gemm_argmin<<<grid, 256, 0, stream>>>(x, key_w, f_h, f_best);

    k_scaleN<<<N_TOKEN / 256, 256, 0, stream>>>(ema_n, out_en);
    k_extract_counts<<<T_TOKENS / 256, 256, 0, stream>>>(f_best, f_idx, out_en);
    k_scaleW<<<(N_TOKEN * (N_EMBED / 4)) / 256, 256, 0, stream>>>(ema_w, out_ew);
    k_quant_scatter<<<(T_TOKENS * (N_EMBED / 4)) / 256, 256, 0, stream>>>(
        x, value_w, f_idx, out_q, out_ew);
    k_sumn<<<1, 256, 0, stream>>>(out_en, f_nsum);
    k_keyw<<<(N_TOKEN * (N_EMBED / 4)) / 256, 256, 0, stream>>>(out_ew, out_en, f_nsum, out_kw);
  }
}